// Round 12
// baseline (400.244 us; speedup 1.0000x reference)
//
#include <hip/hip_runtime.h>
#include <hip/hip_cooperative_groups.h>

namespace cg = cooperative_groups;

#define D_FEAT 64
#define CHUNK 4096        // edges per chunk (NC must be <= 512)
#define NBMAX 512         // max buckets (N <= 131072; also requires N < 2^24 for packing)
#define BNODES 256        // nodes per bucket
#define GBLD 256          // cooperative build grid (co-resident: 1 block/CU guaranteed)

typedef __attribute__((ext_vector_type(8))) short bf16x8;
typedef __attribute__((ext_vector_type(4))) float f32x4;

static __device__ inline short f2bf(float f) {
    unsigned u = __float_as_uint(f);
    u += 0x7fffu + ((u >> 16) & 1u);  // RNE
    return (short)(u >> 16);
}

static __device__ inline void acc8(uint4 u, float* a) {
    a[0] += __uint_as_float(u.x << 16);
    a[1] += __uint_as_float(u.x & 0xffff0000u);
    a[2] += __uint_as_float(u.y << 16);
    a[3] += __uint_as_float(u.y & 0xffff0000u);
    a[4] += __uint_as_float(u.z << 16);
    a[5] += __uint_as_float(u.z & 0xffff0000u);
    a[6] += __uint_as_float(u.w << 16);
    a[7] += __uint_as_float(u.w & 0xffff0000u);
}

static __device__ inline uint4 pack8(const float* a, float s) {
    uint4 r;
    r.x = (unsigned)(unsigned short)f2bf(a[0] * s) | ((unsigned)(unsigned short)f2bf(a[1] * s) << 16);
    r.y = (unsigned)(unsigned short)f2bf(a[2] * s) | ((unsigned)(unsigned short)f2bf(a[3] * s) << 16);
    r.z = (unsigned)(unsigned short)f2bf(a[4] * s) | ((unsigned)(unsigned short)f2bf(a[5] * s) << 16);
    r.w = (unsigned)(unsigned short)f2bf(a[6] * s) | ((unsigned)(unsigned short)f2bf(a[7] * s) << 16);
    return r;
}

// ---------------- fused build: hist -> colscan -> base -> scatter -> csr -> convert ----------------
// One cooperative launch; grid.sync() between phases. 256 blocks x 256 threads.

__global__ __launch_bounds__(256, 2) void build_all_kernel(
    const int* __restrict__ src, const int* __restrict__ dst,
    const float* __restrict__ x,
    int* __restrict__ hist,      // [nc][nb], becomes exclusive chunk-prefix in P2
    int* __restrict__ totals,    // [nb]
    int* __restrict__ bbase,     // [nb+1]
    int* __restrict__ rp, float* __restrict__ dinv, int* __restrict__ col,
    unsigned* __restrict__ pairs,
    uint4* __restrict__ xb, uint4* __restrict__ xs,
    int e, int n, int nb, int nc)
{
    cg::grid_group grid = cg::this_grid();
    __shared__ int sh[NBMAX];    // 2 KB, reused per phase
    __shared__ int sh2[BNODES];  // csr cnt
    __shared__ int sh3[BNODES];  // csr scan
    int tid = threadIdx.x;
    int bid = blockIdx.x;

    // ---- P1: per-chunk bucket histogram ----
    for (int c = bid; c < nc; c += GBLD) {
        for (int i = tid; i < nb; i += 256) sh[i] = 0;
        __syncthreads();
        int base = c * CHUNK, end = min(base + CHUNK, e);
        for (int i = base + tid; i < end; i += 256)
            atomicAdd(&sh[dst[i] >> 8], 1);
        __syncthreads();
        for (int i = tid; i < nb; i += 256)
            hist[(size_t)c * nb + i] = sh[i];
        __syncthreads();
    }
    grid.sync();

    // ---- P2: per-bucket exclusive scan over chunks (in place) + totals ----
    for (int k = bid; k < nb; k += GBLD) {
        for (int i = tid; i < 512; i += 256)
            sh[i] = (i < nc) ? hist[(size_t)i * nb + k] : 0;
        __syncthreads();
        for (int off = 1; off < 512; off <<= 1) {  // inclusive scan, 512 slots / 256 thr
            int t1 = tid + 256;
            int v0 = (tid >= off) ? sh[tid - off] : 0;
            int v1 = (t1 >= off) ? sh[t1 - off] : 0;
            __syncthreads();
            sh[tid] += v0; sh[t1] += v1;
            __syncthreads();
        }
        for (int i = tid; i < nc; i += 256)
            hist[(size_t)i * nb + k] = (i == 0) ? 0 : sh[i - 1];  // exclusive
        if (tid == 0) totals[k] = sh[nc - 1];
        __syncthreads();
    }
    grid.sync();

    // ---- P3: block 0 scans totals -> bbase; rp[n]=e ----
    if (bid == 0) {
        for (int i = tid; i < 512; i += 256) sh[i] = (i < nb) ? totals[i] : 0;
        __syncthreads();
        for (int off = 1; off < 512; off <<= 1) {
            int t1 = tid + 256;
            int v0 = (tid >= off) ? sh[tid - off] : 0;
            int v1 = (t1 >= off) ? sh[t1 - off] : 0;
            __syncthreads();
            sh[tid] += v0; sh[t1] += v1;
            __syncthreads();
        }
        for (int i = tid; i < nb; i += 256)
            bbase[i] = (i == 0) ? 0 : sh[i - 1];
        if (tid == 0) { bbase[nb] = e; rp[n] = e; }
    }
    grid.sync();

    // ---- P4: scatter packed (dlocal<<24 | src) into bucket-contiguous order ----
    for (int c = bid; c < nc; c += GBLD) {
        for (int i = tid; i < nb; i += 256)
            sh[i] = bbase[i] + hist[(size_t)c * nb + i];
        __syncthreads();
        int base = c * CHUNK, end = min(base + CHUNK, e);
        for (int i = base + tid; i < end; i += 256) {
            int d = dst[i];
            int pos = atomicAdd(&sh[d >> 8], 1);
            pairs[pos] = ((unsigned)(d & 255) << 24) | (unsigned)src[i];
        }
        __syncthreads();
    }
    grid.sync();

    // ---- P5: per-bucket CSR build (rp, dinv, col) ----
    for (int k = bid; k < nb; k += GBLD) {
        int node0 = k << 8;
        int e0 = bbase[k], e1 = bbase[k + 1];
        sh2[tid] = 0;
        __syncthreads();
        for (int i = e0 + tid; i < e1; i += 256)
            atomicAdd(&sh2[pairs[i] >> 24], 1);
        __syncthreads();
        int v = sh2[tid];
        sh3[tid] = v;
        __syncthreads();
        for (int off = 1; off < 256; off <<= 1) {
            int u = (tid >= off) ? sh3[tid - off] : 0;
            __syncthreads();
            sh3[tid] += u;
            __syncthreads();
        }
        int excl = sh3[tid] - v;
        sh[tid] = e0 + excl;  // cur
        int node = node0 + tid;
        if (node < n) {
            rp[node] = e0 + excl;
            dinv[node] = rsqrtf(1.0f + (float)v);
        }
        __syncthreads();
        for (int i = e0 + tid; i < e1; i += 256) {
            unsigned p = pairs[i];
            int pos = atomicAdd(&sh[p >> 24], 1);
            col[pos] = (int)(p & 0xFFFFFFu);
        }
        __syncthreads();
    }
    grid.sync();

    // ---- P6: convert xb = bf16(x), xs = bf16(dinv*x) ----
    long long total = (long long)n * 8;
    const float4* x4 = (const float4*)x;
    for (long long t = (long long)bid * 256 + tid; t < total; t += (long long)GBLD * 256) {
        int node = (int)(t >> 3);
        int j = (int)(t & 7);
        float4 a0 = x4[(size_t)node * 16 + j * 2];
        float4 a1 = x4[(size_t)node * 16 + j * 2 + 1];
        float di = dinv[node];
        float a[8] = {a0.x, a0.y, a0.z, a0.w, a1.x, a1.y, a1.z, a1.w};
        size_t o = (size_t)node * 8 + j;
        xb[o] = pack8(a, 1.0f);
        xs[o] = pack8(a, di);
    }
}

// ---------------- hop 1: row-sum of xs; g1b = bf16(di^2*acc) ----------------

__global__ __launch_bounds__(256) void spmm_hop1_kernel(const int* __restrict__ rp,
                                                        const int* __restrict__ col,
                                                        const float* __restrict__ dinv,
                                                        const uint4* __restrict__ xs,
                                                        uint4* __restrict__ g1b, int n) {
    int t = blockIdx.x * 256 + threadIdx.x;
    int node = t >> 3;
    int j = t & 7;
    if (node >= n) return;
    int e0 = rp[node];
    int e1 = rp[node + 1];
    float di = dinv[node];
    float a[8] = {0, 0, 0, 0, 0, 0, 0, 0};
    float c[8] = {0, 0, 0, 0, 0, 0, 0, 0};
    acc8(xs[(size_t)node * 8 + j], a);  // self term
    int e = e0;
    for (; e + 3 < e1; e += 4) {
        int s0 = col[e];
        int s1 = col[e + 1];
        int s2 = col[e + 2];
        int s3 = col[e + 3];
        uint4 u0 = xs[(size_t)s0 * 8 + j];
        uint4 u1 = xs[(size_t)s1 * 8 + j];
        uint4 u2 = xs[(size_t)s2 * 8 + j];
        uint4 u3 = xs[(size_t)s3 * 8 + j];
        acc8(u0, a);
        acc8(u1, c);
        acc8(u2, a);
        acc8(u3, c);
    }
    for (; e < e1; ++e) acc8(xs[(size_t)col[e] * 8 + j], a);
#pragma unroll
    for (int i = 0; i < 8; ++i) a[i] += c[i];
    g1b[(size_t)node * 8 + j] = pack8(a, di * di);
}

// ---------------- hop 2: row-sum of g1b; h2b = bf16(di*acc) ----------------

__global__ __launch_bounds__(256) void spmm_hop2_kernel(const int* __restrict__ rp,
                                                        const int* __restrict__ col,
                                                        const float* __restrict__ dinv,
                                                        const uint4* __restrict__ g1b,
                                                        uint4* __restrict__ h2b, int n) {
    int t = blockIdx.x * 256 + threadIdx.x;
    int node = t >> 3;
    int j = t & 7;
    if (node >= n) return;
    int e0 = rp[node];
    int e1 = rp[node + 1];
    float di = dinv[node];
    float a[8] = {0, 0, 0, 0, 0, 0, 0, 0};
    float c[8] = {0, 0, 0, 0, 0, 0, 0, 0};
    acc8(g1b[(size_t)node * 8 + j], a);
    int e = e0;
    for (; e + 3 < e1; e += 4) {
        int s0 = col[e];
        int s1 = col[e + 1];
        int s2 = col[e + 2];
        int s3 = col[e + 3];
        uint4 u0 = g1b[(size_t)s0 * 8 + j];
        uint4 u1 = g1b[(size_t)s1 * 8 + j];
        uint4 u2 = g1b[(size_t)s2 * 8 + j];
        uint4 u3 = g1b[(size_t)s3 * 8 + j];
        acc8(u0, a);
        acc8(u1, c);
        acc8(u2, a);
        acc8(u3, c);
    }
    for (; e < e1; ++e) acc8(g1b[(size_t)col[e] * 8 + j], a);
#pragma unroll
    for (int i = 0; i < 8; ++i) a[i] += c[i];
    h2b[(size_t)node * 8 + j] = pack8(a, di);
}

// ---------------- output GEMM via bf16 MFMA, dual accumulator ----------------
// out = x@W0 + diag(1/dinv)*(g1@W1) + h2@W2 + b

#define WT_LD 200

__global__ __launch_bounds__(256) void gemm_mfma_kernel(const unsigned short* __restrict__ xb,
                                                        const unsigned short* __restrict__ g1b,
                                                        const unsigned short* __restrict__ h2b,
                                                        const float* __restrict__ dinv,
                                                        const float* __restrict__ W,
                                                        const float* __restrict__ b,
                                                        float* __restrict__ out, int n) {
    __shared__ short sWt[64 * WT_LD];
    int tid = threadIdx.x;

    for (int i = tid; i < 192 * 64; i += 256) {
        int k = i >> 6;
        int c = i & 63;
        sWt[c * WT_LD + k] = f2bf(W[i]);
    }
    __syncthreads();

    int w = tid >> 6;
    int l = tid & 63;
    int lr = l & 15;
    int lk = l >> 4;
    int rbase = blockIdx.x * 64 + w * 16;

    int node = rbase + lr;
    int node_ld = node < n ? node : (n - 1);

    f32x4 accA[4] = {{0.f, 0.f, 0.f, 0.f}, {0.f, 0.f, 0.f, 0.f},
                     {0.f, 0.f, 0.f, 0.f}, {0.f, 0.f, 0.f, 0.f}};
    f32x4 accB[4] = {{0.f, 0.f, 0.f, 0.f}, {0.f, 0.f, 0.f, 0.f},
                     {0.f, 0.f, 0.f, 0.f}, {0.f, 0.f, 0.f, 0.f}};

    const unsigned short* srcs[3] = {xb, g1b, h2b};
#pragma unroll
    for (int kt = 0; kt < 6; ++kt) {
        const unsigned short* sp = srcs[kt >> 1];
        int kb = (kt & 1) * 32 + lk * 8;
        bf16x8 af = *(const bf16x8*)(sp + (size_t)node_ld * D_FEAT + kb);
        int kg = kt * 32 + lk * 8;
#pragma unroll
        for (int nt = 0; nt < 4; ++nt) {
            int c = nt * 16 + lr;
            bf16x8 bf = *(const bf16x8*)&sWt[c * WT_LD + kg];
            if ((kt >> 1) == 1)
                accB[nt] = __builtin_amdgcn_mfma_f32_16x16x32_bf16(af, bf, accB[nt], 0, 0, 0);
            else
                accA[nt] = __builtin_amdgcn_mfma_f32_16x16x32_bf16(af, bf, accA[nt], 0, 0, 0);
        }
    }

    float sd[4];
#pragma unroll
    for (int i = 0; i < 4; ++i) {
        int row = rbase + lk * 4 + i;
        sd[i] = (row < n) ? (1.0f / dinv[row]) : 0.0f;
    }

#pragma unroll
    for (int nt = 0; nt < 4; ++nt) {
        int c = nt * 16 + lr;
        float bias = b[c];
#pragma unroll
        for (int i = 0; i < 4; ++i) {
            int row = rbase + lk * 4 + i;
            if (row < n)
                out[(size_t)row * D_FEAT + c] = accA[nt][i] + sd[i] * accB[nt][i] + bias;
        }
    }
}

// ---------------- launch ----------------

static inline size_t align256(size_t x) { return (x + 255) & ~(size_t)255; }

extern "C" void kernel_launch(void* const* d_in, const int* in_sizes, int n_in,
                              void* d_out, int out_size, void* d_ws, size_t ws_size,
                              hipStream_t stream) {
    const float* x  = (const float*)d_in[0];
    const int*   ei = (const int*)d_in[1];
    const float* W  = (const float*)d_in[2];
    const float* b  = (const float*)d_in[3];
    float* out = (float*)d_out;

    int N = in_sizes[0] / D_FEAT;
    int E = in_sizes[1] / 2;
    const int* src = ei;
    const int* dst = ei + E;

    int NB = (N + BNODES - 1) / BNODES;   // 391 for N=100000 (<=512)
    int NC = (E + CHUNK - 1) / CHUNK;     // 391 for E=1.6M   (<=512)

    char* base = (char*)d_ws;
    size_t off = 0;
    int* rp      = (int*)(base + off);   off = align256(off + ((size_t)N + 1) * 4);
    float* dinv  = (float*)(base + off); off = align256(off + (size_t)N * 4);
    int* totals  = (int*)(base + off);   off = align256(off + (size_t)NBMAX * 4);
    int* bbase   = (int*)(base + off);   off = align256(off + (size_t)(NBMAX + 1) * 4);
    int* col     = (int*)(base + off);   off = align256(off + (size_t)E * 4);
    uint4* xb    = (uint4*)(base + off); off = align256(off + (size_t)N * D_FEAT * 2);
    uint4* xs    = (uint4*)(base + off); off = align256(off + (size_t)N * D_FEAT * 2);
    uint4* g1b   = (uint4*)(base + off); off = align256(off + (size_t)N * D_FEAT * 2);
    uint4* h2b   = (uint4*)(base + off); off = align256(off + (size_t)N * D_FEAT * 2);
    // transient build arrays beyond the persistent spans (coexist during build):
    unsigned* pairs = (unsigned*)(base + off);  // E*4 = 6.4 MB
    int* hist    = (int*)((char*)pairs + align256((size_t)E * 4));  // NC*NB*4

    const int BS = 256;
    int gN8 = (int)(((long long)N * 8 + BS - 1) / BS);
    int gGemm = (N + 63) / 64;

    void* args[] = {(void*)&src, (void*)&dst, (void*)&x,
                    (void*)&hist, (void*)&totals, (void*)&bbase,
                    (void*)&rp, (void*)&dinv, (void*)&col,
                    (void*)&pairs, (void*)&xb, (void*)&xs,
                    (void*)&E, (void*)&N, (void*)&NB, (void*)&NC};
    hipLaunchCooperativeKernel((const void*)build_all_kernel, dim3(GBLD), dim3(BS),
                               args, 0, stream);

    spmm_hop1_kernel<<<gN8, BS, 0, stream>>>(rp, col, dinv, xs, g1b, N);
    spmm_hop2_kernel<<<gN8, BS, 0, stream>>>(rp, col, dinv, g1b, h2b, N);
    gemm_mfma_kernel<<<gGemm, BS, 0, stream>>>((const unsigned short*)xb,
                                               (const unsigned short*)g1b,
                                               (const unsigned short*)h2b,
                                               dinv, W, b, out, N);
}

// Round 13
// 244.883 us; speedup vs baseline: 1.6344x; 1.6344x over previous
//
#include <hip/hip_runtime.h>

#define D_FEAT 64
#define CHUNK 4096        // edges per chunk (NC must be <= 512)
#define NBMAX 512         // max buckets (N <= 131072; N < 2^24 for packing)
#define BNODES 256        // nodes per bucket

typedef __attribute__((ext_vector_type(8))) short bf16x8;
typedef __attribute__((ext_vector_type(4))) float f32x4;

static __device__ inline short f2bf(float f) {
    unsigned u = __float_as_uint(f);
    u += 0x7fffu + ((u >> 16) & 1u);  // RNE
    return (short)(u >> 16);
}

static __device__ inline void acc8(uint4 u, float* a) {
    a[0] += __uint_as_float(u.x << 16);
    a[1] += __uint_as_float(u.x & 0xffff0000u);
    a[2] += __uint_as_float(u.y << 16);
    a[3] += __uint_as_float(u.y & 0xffff0000u);
    a[4] += __uint_as_float(u.z << 16);
    a[5] += __uint_as_float(u.z & 0xffff0000u);
    a[6] += __uint_as_float(u.w << 16);
    a[7] += __uint_as_float(u.w & 0xffff0000u);
}

static __device__ inline uint4 pack8(const float* a, float s) {
    uint4 r;
    r.x = (unsigned)(unsigned short)f2bf(a[0] * s) | ((unsigned)(unsigned short)f2bf(a[1] * s) << 16);
    r.y = (unsigned)(unsigned short)f2bf(a[2] * s) | ((unsigned)(unsigned short)f2bf(a[3] * s) << 16);
    r.z = (unsigned)(unsigned short)f2bf(a[4] * s) | ((unsigned)(unsigned short)f2bf(a[5] * s) << 16);
    r.w = (unsigned)(unsigned short)f2bf(a[6] * s) | ((unsigned)(unsigned short)f2bf(a[7] * s) << 16);
    return r;
}

// ---------------- P1: per-chunk bucket histogram (LDS-privatized) ----------------

__global__ __launch_bounds__(256) void hist_kernel(const int* __restrict__ dst,
                                                   int* __restrict__ hist, int e, int nb) {
    __shared__ int hs[NBMAX];
    int tid = threadIdx.x;
    for (int i = tid; i < nb; i += 256) hs[i] = 0;
    __syncthreads();
    int base = blockIdx.x * CHUNK;
    int end = min(base + CHUNK, e);
    for (int i = base + tid; i < end; i += 256)
        atomicAdd(&hs[dst[i] >> 8], 1);
    __syncthreads();
    for (int i = tid; i < nb; i += 256)
        hist[(size_t)blockIdx.x * nb + i] = hs[i];
}

// ---------------- K2a: per-bucket exclusive scan over chunks + totals ----------------

__global__ __launch_bounds__(512) void colscan_kernel(int* __restrict__ hist,
                                                      int* __restrict__ totals,
                                                      int nc, int nb) {
    __shared__ int s[512];
    int k = blockIdx.x;
    int t = threadIdx.x;
    int v = (t < nc) ? hist[(size_t)t * nb + k] : 0;
    s[t] = v;
    __syncthreads();
    for (int off = 1; off < 512; off <<= 1) {
        int u = (t >= off) ? s[t - off] : 0;
        __syncthreads();
        s[t] += u;
        __syncthreads();
    }
    if (t < nc) hist[(size_t)t * nb + k] = s[t] - v;
    if (t == nc - 1) totals[k] = s[t];
}

// ---------------- K2b: scan totals -> bbase; rp[N]=E; zero deg bins ----------------

__global__ __launch_bounds__(512) void base_kernel(const int* __restrict__ totals,
                                                   int* __restrict__ bbase,
                                                   int* __restrict__ rp,
                                                   int* __restrict__ dbins,
                                                   int nb, int n, int e) {
    __shared__ int s[512];
    int t = threadIdx.x;
    int v = (t < nb) ? totals[t] : 0;
    s[t] = v;
    __syncthreads();
    for (int off = 1; off < 512; off <<= 1) {
        int u = (t >= off) ? s[t - off] : 0;
        __syncthreads();
        s[t] += u;
        __syncthreads();
    }
    if (t < nb) bbase[t] = s[t] - v;
    if (t < 256) dbins[t] = 0;
    if (t == 0) {
        bbase[nb] = e;
        rp[n] = e;
    }
}

// ---------------- P3: scatter packed (dlocal<<24 | src) ----------------

__global__ __launch_bounds__(256) void scatter_kernel(const int* __restrict__ src,
                                                      const int* __restrict__ dst,
                                                      const int* __restrict__ pref,
                                                      const int* __restrict__ bbase,
                                                      unsigned* __restrict__ pairs,
                                                      int e, int nb) {
    __shared__ int cur[NBMAX];
    int tid = threadIdx.x;
    int b = blockIdx.x;
    for (int i = tid; i < nb; i += 256)
        cur[i] = bbase[i] + pref[(size_t)b * nb + i];
    __syncthreads();
    int base = b * CHUNK;
    int end = min(base + CHUNK, e);
    for (int i = base + tid; i < end; i += 256) {
        int d = dst[i];
        int pos = atomicAdd(&cur[d >> 8], 1);
        pairs[pos] = ((unsigned)(d & 255) << 24) | (unsigned)src[i];
    }
}

// ---------------- P4: per-bucket CSR build + fused bf16 convert ----------------

__global__ __launch_bounds__(256) void csr_conv_kernel(const unsigned* __restrict__ pairs,
                                                       const int* __restrict__ bbase,
                                                       const float* __restrict__ x,
                                                       int* __restrict__ rp,
                                                       float* __restrict__ dinv,
                                                       int* __restrict__ col,
                                                       uint4* __restrict__ xb,
                                                       uint4* __restrict__ xs, int n) {
    __shared__ int cnt[BNODES];
    __shared__ int s[BNODES];
    __shared__ int cur[BNODES];
    __shared__ float sdv[BNODES];
    int tid = threadIdx.x;
    int k = blockIdx.x;
    int node0 = k << 8;
    int e0 = bbase[k];
    int e1 = bbase[k + 1];
    cnt[tid] = 0;
    __syncthreads();
    for (int i = e0 + tid; i < e1; i += 256)
        atomicAdd(&cnt[pairs[i] >> 24], 1);
    __syncthreads();
    int v = cnt[tid];
    s[tid] = v;
    __syncthreads();
    for (int off = 1; off < 256; off <<= 1) {
        int u = (tid >= off) ? s[tid - off] : 0;
        __syncthreads();
        s[tid] += u;
        __syncthreads();
    }
    int excl = s[tid] - v;
    cur[tid] = e0 + excl;
    float dv = rsqrtf(1.0f + (float)v);
    sdv[tid] = dv;
    int node = node0 + tid;
    if (node < n) {
        rp[node] = e0 + excl;
        dinv[node] = dv;
    }
    __syncthreads();
    for (int i = e0 + tid; i < e1; i += 256) {
        unsigned p = pairs[i];
        int pos = atomicAdd(&cur[p >> 24], 1);
        col[pos] = (int)(p & 0xFFFFFFu);
    }
    // fused convert for this bucket's nodes (coalesced x reads)
    const float4* x4 = (const float4*)x;
    for (int t = tid; t < BNODES * 8; t += 256) {
        int nl = t >> 3;
        int j = t & 7;
        int nd = node0 + nl;
        if (nd < n) {
            float4 a0 = x4[(size_t)nd * 16 + j * 2];
            float4 a1 = x4[(size_t)nd * 16 + j * 2 + 1];
            float di = sdv[nl];
            float a[8] = {a0.x, a0.y, a0.z, a0.w, a1.x, a1.y, a1.z, a1.w};
            size_t o = (size_t)nd * 8 + j;
            xb[o] = pack8(a, 1.0f);
            xs[o] = pack8(a, di);
        }
    }
}

// ---------------- degree-sort permutation (3 small kernels) ----------------

__global__ __launch_bounds__(256) void deghist_kernel(const int* __restrict__ rp,
                                                      int* __restrict__ dbins, int n) {
    __shared__ int hs[256];
    int tid = threadIdx.x;
    hs[tid] = 0;
    __syncthreads();
    int i = blockIdx.x * 256 + tid;
    if (i < n) {
        int d = rp[i + 1] - rp[i];
        atomicAdd(&hs[d > 255 ? 255 : d], 1);
    }
    __syncthreads();
    if (hs[tid]) atomicAdd(&dbins[tid], hs[tid]);
}

__global__ __launch_bounds__(256) void degbase_kernel(const int* __restrict__ dbins,
                                                      int* __restrict__ dcur) {
    __shared__ int s[256];
    int tid = threadIdx.x;
    int v = dbins[tid];
    s[tid] = v;
    __syncthreads();
    for (int off = 1; off < 256; off <<= 1) {
        int u = (tid >= off) ? s[tid - off] : 0;
        __syncthreads();
        s[tid] += u;
        __syncthreads();
    }
    dcur[tid] = s[tid] - v;  // exclusive base, doubles as cursor
}

__global__ __launch_bounds__(256) void degplace_kernel(const int* __restrict__ rp,
                                                       int* __restrict__ dcur,
                                                       int* __restrict__ perm, int n) {
    __shared__ int hs[256];
    __shared__ int base[256];
    int tid = threadIdx.x;
    hs[tid] = 0;
    __syncthreads();
    int i = blockIdx.x * 256 + tid;
    int bin = 0, off = 0;
    if (i < n) {
        int d = rp[i + 1] - rp[i];
        bin = d > 255 ? 255 : d;
        off = atomicAdd(&hs[bin], 1);
    }
    __syncthreads();
    if (hs[tid]) base[tid] = atomicAdd(&dcur[tid], hs[tid]);
    __syncthreads();
    if (i < n) perm[base[bin] + off] = i;
}

// ---------------- hop 1: row-sum of xs over perm order; g1b = bf16(di^2*acc) ----------------

__global__ __launch_bounds__(256) void spmm_hop1_kernel(const int* __restrict__ perm,
                                                        const int* __restrict__ rp,
                                                        const int* __restrict__ col,
                                                        const float* __restrict__ dinv,
                                                        const uint4* __restrict__ xs,
                                                        uint4* __restrict__ g1b, int n) {
    int t = blockIdx.x * 256 + threadIdx.x;
    int nidx = t >> 3;
    int j = t & 7;
    if (nidx >= n) return;
    int node = perm[nidx];
    int e0 = rp[node];
    int e1 = rp[node + 1];
    float di = dinv[node];
    float a[8] = {0, 0, 0, 0, 0, 0, 0, 0};
    float c[8] = {0, 0, 0, 0, 0, 0, 0, 0};
    acc8(xs[(size_t)node * 8 + j], a);  // self term
    int e = e0;
    for (; e + 3 < e1; e += 4) {
        int s0 = col[e];
        int s1 = col[e + 1];
        int s2 = col[e + 2];
        int s3 = col[e + 3];
        uint4 u0 = xs[(size_t)s0 * 8 + j];
        uint4 u1 = xs[(size_t)s1 * 8 + j];
        uint4 u2 = xs[(size_t)s2 * 8 + j];
        uint4 u3 = xs[(size_t)s3 * 8 + j];
        acc8(u0, a);
        acc8(u1, c);
        acc8(u2, a);
        acc8(u3, c);
    }
    for (; e < e1; ++e) acc8(xs[(size_t)col[e] * 8 + j], a);
#pragma unroll
    for (int i = 0; i < 8; ++i) a[i] += c[i];
    g1b[(size_t)node * 8 + j] = pack8(a, di * di);
}

// ---------------- hop 2: row-sum of g1b over perm order; h2b = bf16(di*acc) ----------------

__global__ __launch_bounds__(256) void spmm_hop2_kernel(const int* __restrict__ perm,
                                                        const int* __restrict__ rp,
                                                        const int* __restrict__ col,
                                                        const float* __restrict__ dinv,
                                                        const uint4* __restrict__ g1b,
                                                        uint4* __restrict__ h2b, int n) {
    int t = blockIdx.x * 256 + threadIdx.x;
    int nidx = t >> 3;
    int j = t & 7;
    if (nidx >= n) return;
    int node = perm[nidx];
    int e0 = rp[node];
    int e1 = rp[node + 1];
    float di = dinv[node];
    float a[8] = {0, 0, 0, 0, 0, 0, 0, 0};
    float c[8] = {0, 0, 0, 0, 0, 0, 0, 0};
    acc8(g1b[(size_t)node * 8 + j], a);
    int e = e0;
    for (; e + 3 < e1; e += 4) {
        int s0 = col[e];
        int s1 = col[e + 1];
        int s2 = col[e + 2];
        int s3 = col[e + 3];
        uint4 u0 = g1b[(size_t)s0 * 8 + j];
        uint4 u1 = g1b[(size_t)s1 * 8 + j];
        uint4 u2 = g1b[(size_t)s2 * 8 + j];
        uint4 u3 = g1b[(size_t)s3 * 8 + j];
        acc8(u0, a);
        acc8(u1, c);
        acc8(u2, a);
        acc8(u3, c);
    }
    for (; e < e1; ++e) acc8(g1b[(size_t)col[e] * 8 + j], a);
#pragma unroll
    for (int i = 0; i < 8; ++i) a[i] += c[i];
    h2b[(size_t)node * 8 + j] = pack8(a, di);
}

// ---------------- output GEMM via bf16 MFMA, dual accumulator ----------------
// out = x@W0 + diag(1/dinv)*(g1@W1) + h2@W2 + b

#define WT_LD 200

__global__ __launch_bounds__(256) void gemm_mfma_kernel(const unsigned short* __restrict__ xb,
                                                        const unsigned short* __restrict__ g1b,
                                                        const unsigned short* __restrict__ h2b,
                                                        const float* __restrict__ dinv,
                                                        const float* __restrict__ W,
                                                        const float* __restrict__ b,
                                                        float* __restrict__ out, int n) {
    __shared__ short sWt[64 * WT_LD];
    int tid = threadIdx.x;

    for (int i = tid; i < 192 * 64; i += 256) {
        int k = i >> 6;
        int c = i & 63;
        sWt[c * WT_LD + k] = f2bf(W[i]);
    }
    __syncthreads();

    int w = tid >> 6;
    int l = tid & 63;
    int lr = l & 15;
    int lk = l >> 4;
    int rbase = blockIdx.x * 64 + w * 16;

    int node = rbase + lr;
    int node_ld = node < n ? node : (n - 1);

    f32x4 accA[4] = {{0.f, 0.f, 0.f, 0.f}, {0.f, 0.f, 0.f, 0.f},
                     {0.f, 0.f, 0.f, 0.f}, {0.f, 0.f, 0.f, 0.f}};
    f32x4 accB[4] = {{0.f, 0.f, 0.f, 0.f}, {0.f, 0.f, 0.f, 0.f},
                     {0.f, 0.f, 0.f, 0.f}, {0.f, 0.f, 0.f, 0.f}};

    const unsigned short* srcs[3] = {xb, g1b, h2b};
#pragma unroll
    for (int kt = 0; kt < 6; ++kt) {
        const unsigned short* sp = srcs[kt >> 1];
        int kb = (kt & 1) * 32 + lk * 8;
        bf16x8 af = *(const bf16x8*)(sp + (size_t)node_ld * D_FEAT + kb);
        int kg = kt * 32 + lk * 8;
#pragma unroll
        for (int nt = 0; nt < 4; ++nt) {
            int c = nt * 16 + lr;
            bf16x8 bf = *(const bf16x8*)&sWt[c * WT_LD + kg];
            if ((kt >> 1) == 1)
                accB[nt] = __builtin_amdgcn_mfma_f32_16x16x32_bf16(af, bf, accB[nt], 0, 0, 0);
            else
                accA[nt] = __builtin_amdgcn_mfma_f32_16x16x32_bf16(af, bf, accA[nt], 0, 0, 0);
        }
    }

    float sd[4];
#pragma unroll
    for (int i = 0; i < 4; ++i) {
        int row = rbase + lk * 4 + i;
        sd[i] = (row < n) ? (1.0f / dinv[row]) : 0.0f;
    }

#pragma unroll
    for (int nt = 0; nt < 4; ++nt) {
        int c = nt * 16 + lr;
        float bias = b[c];
#pragma unroll
        for (int i = 0; i < 4; ++i) {
            int row = rbase + lk * 4 + i;
            if (row < n)
                out[(size_t)row * D_FEAT + c] = accA[nt][i] + sd[i] * accB[nt][i] + bias;
        }
    }
}

// ---------------- launch ----------------

static inline size_t align256(size_t x) { return (x + 255) & ~(size_t)255; }

extern "C" void kernel_launch(void* const* d_in, const int* in_sizes, int n_in,
                              void* d_out, int out_size, void* d_ws, size_t ws_size,
                              hipStream_t stream) {
    const float* x  = (const float*)d_in[0];
    const int*   ei = (const int*)d_in[1];
    const float* W  = (const float*)d_in[2];
    const float* b  = (const float*)d_in[3];
    float* out = (float*)d_out;

    int N = in_sizes[0] / D_FEAT;
    int E = in_sizes[1] / 2;
    const int* src = ei;
    const int* dst = ei + E;

    int NB = (N + BNODES - 1) / BNODES;   // 391 for N=100000 (<=512)
    int NC = (E + CHUNK - 1) / CHUNK;     // 391 for E=1.6M   (<=512)

    char* base = (char*)d_ws;
    size_t off = 0;
    int* rp      = (int*)(base + off);   off = align256(off + ((size_t)N + 1) * 4);
    float* dinv  = (float*)(base + off); off = align256(off + (size_t)N * 4);
    int* totals  = (int*)(base + off);   off = align256(off + (size_t)NBMAX * 4);
    int* bbase   = (int*)(base + off);   off = align256(off + (size_t)(NBMAX + 1) * 4);
    int* dbins   = (int*)(base + off);   off = align256(off + 256 * 4);
    int* dcur    = (int*)(base + off);   off = align256(off + 256 * 4);
    int* perm    = (int*)(base + off);   off = align256(off + (size_t)N * 4);
    int* col     = (int*)(base + off);   off = align256(off + (size_t)E * 4);
    uint4* xb    = (uint4*)(base + off); off = align256(off + (size_t)N * D_FEAT * 2);
    uint4* xs    = (uint4*)(base + off); off = align256(off + (size_t)N * D_FEAT * 2);
    uint4* g1b   = (uint4*)(base + off); off = align256(off + (size_t)N * D_FEAT * 2);
    uint4* h2b   = (uint4*)(base + off); off = align256(off + (size_t)N * D_FEAT * 2);
    // transient build arrays beyond the persistent spans:
    unsigned* pairs = (unsigned*)(base + off);  // E*4 = 6.4 MB, dead after csr_conv
    int* hist    = (int*)((char*)pairs + align256((size_t)E * 4));  // NC*NB*4

    const int BS = 256;
    int gN1 = (N + BS - 1) / BS;
    int gN8 = (int)(((long long)N * 8 + BS - 1) / BS);
    int gGemm = (N + 63) / 64;

    hist_kernel<<<NC, BS, 0, stream>>>(dst, hist, E, NB);
    colscan_kernel<<<NB, 512, 0, stream>>>(hist, totals, NC, NB);
    base_kernel<<<1, 512, 0, stream>>>(totals, bbase, rp, dbins, NB, N, E);
    scatter_kernel<<<NC, BS, 0, stream>>>(src, dst, hist, bbase, pairs, E, NB);
    csr_conv_kernel<<<NB, BS, 0, stream>>>(pairs, bbase, x, rp, dinv, col, xb, xs, N);
    deghist_kernel<<<gN1, BS, 0, stream>>>(rp, dbins, N);
    degbase_kernel<<<1, BS, 0, stream>>>(dbins, dcur);
    degplace_kernel<<<gN1, BS, 0, stream>>>(rp, dcur, perm, N);
    spmm_hop1_kernel<<<gN8, BS, 0, stream>>>(perm, rp, col, dinv, xs, g1b, N);
    spmm_hop2_kernel<<<gN8, BS, 0, stream>>>(perm, rp, col, dinv, g1b, h2b, N);
    gemm_mfma_kernel<<<gGemm, BS, 0, stream>>>((const unsigned short*)xb,
                                               (const unsigned short*)g1b,
                                               (const unsigned short*)h2b,
                                               dinv, W, b, out, N);
}

// Round 14
// 218.735 us; speedup vs baseline: 1.8298x; 1.1195x over previous
//
#include <hip/hip_runtime.h>

#define D_FEAT 64
#define CHUNK 4096        // edges per chunk (NC must be <= 512)
#define NBMAX 512         // max buckets (N <= 131072; N < 2^24 for packing)
#define BNODES 256        // nodes per bucket

typedef __attribute__((ext_vector_type(8))) short bf16x8;
typedef __attribute__((ext_vector_type(4))) float f32x4;

static __device__ inline short f2bf(float f) {
    unsigned u = __float_as_uint(f);
    u += 0x7fffu + ((u >> 16) & 1u);  // RNE
    return (short)(u >> 16);
}

static __device__ inline void acc8(uint4 u, float* a) {
    a[0] += __uint_as_float(u.x << 16);
    a[1] += __uint_as_float(u.x & 0xffff0000u);
    a[2] += __uint_as_float(u.y << 16);
    a[3] += __uint_as_float(u.y & 0xffff0000u);
    a[4] += __uint_as_float(u.z << 16);
    a[5] += __uint_as_float(u.z & 0xffff0000u);
    a[6] += __uint_as_float(u.w << 16);
    a[7] += __uint_as_float(u.w & 0xffff0000u);
}

static __device__ inline uint4 pack8(const float* a, float s) {
    uint4 r;
    r.x = (unsigned)(unsigned short)f2bf(a[0] * s) | ((unsigned)(unsigned short)f2bf(a[1] * s) << 16);
    r.y = (unsigned)(unsigned short)f2bf(a[2] * s) | ((unsigned)(unsigned short)f2bf(a[3] * s) << 16);
    r.z = (unsigned)(unsigned short)f2bf(a[4] * s) | ((unsigned)(unsigned short)f2bf(a[5] * s) << 16);
    r.w = (unsigned)(unsigned short)f2bf(a[6] * s) | ((unsigned)(unsigned short)f2bf(a[7] * s) << 16);
    return r;
}

// ---- e4m3fn software encode (RNE, subnormals flushed, clamp to 448) ----
static __device__ inline unsigned enc_e4m3(float v) {
    unsigned bits = __float_as_uint(v);
    unsigned aw = bits & 0x7fffffffu;
    unsigned em = 0;
    if (__uint_as_float(aw) >= 0.015625f) {   // >= 2^-6: normal range
        unsigned r = aw + 0x7FFFFu + ((aw >> 20) & 1u);  // RNE at bit 20
        int t = (int)(r >> 20) - 960;                    // (E-120)<<3 | m3
        em = t > 126 ? 126u : (unsigned)t;
    }
    return ((bits >> 31) << 7) | em;
}

// decode-accumulate 8 e4m3 bytes; values carried at 2^-120 scale (fold-out later)
static __device__ inline void accf8(uint2 u, float* a) {
    unsigned w0 = u.x, w1 = u.y;
    a[0] += __uint_as_float(((w0 & 0x80u) << 24)       | ((w0 & 0x7fu) << 20));
    a[1] += __uint_as_float(((w0 & 0x8000u) << 16)     | ((w0 & 0x7f00u) << 12));
    a[2] += __uint_as_float(((w0 & 0x800000u) << 8)    | ((w0 & 0x7f0000u) << 4));
    a[3] += __uint_as_float((w0 & 0x80000000u)         | ((w0 & 0x7f000000u) >> 4));
    a[4] += __uint_as_float(((w1 & 0x80u) << 24)       | ((w1 & 0x7fu) << 20));
    a[5] += __uint_as_float(((w1 & 0x8000u) << 16)     | ((w1 & 0x7f00u) << 12));
    a[6] += __uint_as_float(((w1 & 0x800000u) << 8)    | ((w1 & 0x7f0000u) << 4));
    a[7] += __uint_as_float((w1 & 0x80000000u)         | ((w1 & 0x7f000000u) >> 4));
}

// ---------------- P1: per-chunk bucket histogram (LDS-privatized) ----------------

__global__ __launch_bounds__(256) void hist_kernel(const int* __restrict__ dst,
                                                   int* __restrict__ hist, int e, int nb) {
    __shared__ int hs[NBMAX];
    int tid = threadIdx.x;
    for (int i = tid; i < nb; i += 256) hs[i] = 0;
    __syncthreads();
    int base = blockIdx.x * CHUNK;
    int end = min(base + CHUNK, e);
    for (int i = base + tid; i < end; i += 256)
        atomicAdd(&hs[dst[i] >> 8], 1);
    __syncthreads();
    for (int i = tid; i < nb; i += 256)
        hist[(size_t)blockIdx.x * nb + i] = hs[i];
}

// ---------------- K2a: per-bucket exclusive scan over chunks + totals ----------------

__global__ __launch_bounds__(512) void colscan_kernel(int* __restrict__ hist,
                                                      int* __restrict__ totals,
                                                      int nc, int nb) {
    __shared__ int s[512];
    int k = blockIdx.x;
    int t = threadIdx.x;
    int v = (t < nc) ? hist[(size_t)t * nb + k] : 0;
    s[t] = v;
    __syncthreads();
    for (int off = 1; off < 512; off <<= 1) {
        int u = (t >= off) ? s[t - off] : 0;
        __syncthreads();
        s[t] += u;
        __syncthreads();
    }
    if (t < nc) hist[(size_t)t * nb + k] = s[t] - v;
    if (t == nc - 1) totals[k] = s[t];
}

// ---------------- K2b: scan totals -> bbase; rp[N]=E ----------------

__global__ __launch_bounds__(512) void base_kernel(const int* __restrict__ totals,
                                                   int* __restrict__ bbase,
                                                   int* __restrict__ rp,
                                                   int nb, int n, int e) {
    __shared__ int s[512];
    int t = threadIdx.x;
    int v = (t < nb) ? totals[t] : 0;
    s[t] = v;
    __syncthreads();
    for (int off = 1; off < 512; off <<= 1) {
        int u = (t >= off) ? s[t - off] : 0;
        __syncthreads();
        s[t] += u;
        __syncthreads();
    }
    if (t < nb) bbase[t] = s[t] - v;
    if (t == 0) {
        bbase[nb] = e;
        rp[n] = e;
    }
}

// ---------------- P3: scatter packed (dlocal<<24 | src) ----------------

__global__ __launch_bounds__(256) void scatter_kernel(const int* __restrict__ src,
                                                      const int* __restrict__ dst,
                                                      const int* __restrict__ pref,
                                                      const int* __restrict__ bbase,
                                                      unsigned* __restrict__ pairs,
                                                      int e, int nb) {
    __shared__ int cur[NBMAX];
    int tid = threadIdx.x;
    int b = blockIdx.x;
    for (int i = tid; i < nb; i += 256)
        cur[i] = bbase[i] + pref[(size_t)b * nb + i];
    __syncthreads();
    int base = b * CHUNK;
    int end = min(base + CHUNK, e);
    for (int i = base + tid; i < end; i += 256) {
        int d = dst[i];
        int pos = atomicAdd(&cur[d >> 8], 1);
        pairs[pos] = ((unsigned)(d & 255) << 24) | (unsigned)src[i];
    }
}

// ---------------- P4: per-bucket CSR build (rp, dinv, col) ----------------

__global__ __launch_bounds__(256) void csr_kernel(const unsigned* __restrict__ pairs,
                                                  const int* __restrict__ bbase,
                                                  int* __restrict__ rp,
                                                  float* __restrict__ dinv,
                                                  int* __restrict__ col, int n) {
    __shared__ int cnt[BNODES];
    __shared__ int s[BNODES];
    __shared__ int cur[BNODES];
    int tid = threadIdx.x;
    int k = blockIdx.x;
    int node0 = k << 8;
    int e0 = bbase[k];
    int e1 = bbase[k + 1];
    cnt[tid] = 0;
    __syncthreads();
    for (int i = e0 + tid; i < e1; i += 256)
        atomicAdd(&cnt[pairs[i] >> 24], 1);
    __syncthreads();
    int v = cnt[tid];
    s[tid] = v;
    __syncthreads();
    for (int off = 1; off < 256; off <<= 1) {
        int u = (tid >= off) ? s[tid - off] : 0;
        __syncthreads();
        s[tid] += u;
        __syncthreads();
    }
    int excl = s[tid] - v;
    cur[tid] = e0 + excl;
    int node = node0 + tid;
    if (node < n) {
        rp[node] = e0 + excl;
        dinv[node] = rsqrtf(1.0f + (float)v);
    }
    __syncthreads();
    for (int i = e0 + tid; i < e1; i += 256) {
        unsigned p = pairs[i];
        int pos = atomicAdd(&cur[p >> 24], 1);
        col[pos] = (int)(p & 0xFFFFFFu);
    }
}

// ---------------- convert: xb = bf16(x), xs = bf16(dinv*x) ----------------

__global__ __launch_bounds__(256) void convert_kernel(const float* __restrict__ x,
                                                      const float* __restrict__ dinv,
                                                      uint4* __restrict__ xb,
                                                      uint4* __restrict__ xs, int n) {
    int t = blockIdx.x * 256 + threadIdx.x;
    int node = t >> 3;
    int j = t & 7;
    if (node >= n) return;
    const float4* x4 = (const float4*)x;
    float4 a0 = x4[(size_t)node * 16 + j * 2];
    float4 a1 = x4[(size_t)node * 16 + j * 2 + 1];
    float di = dinv[node];
    float a[8] = {a0.x, a0.y, a0.z, a0.w, a1.x, a1.y, a1.z, a1.w};
    size_t o = (size_t)node * 8 + j;
    xb[o] = pack8(a, 1.0f);
    xs[o] = pack8(a, di);
}

// ---------------- hop 1: row-sum of xs; g1b = bf16(di^2*acc), g1f8 = e4m3(16*di^2*acc) ----------------

__global__ __launch_bounds__(256) void spmm_hop1_kernel(const int* __restrict__ rp,
                                                        const int* __restrict__ col,
                                                        const float* __restrict__ dinv,
                                                        const uint4* __restrict__ xs,
                                                        uint4* __restrict__ g1b,
                                                        uint2* __restrict__ g1f8, int n) {
    int t = blockIdx.x * 256 + threadIdx.x;
    int node = t >> 3;
    int j = t & 7;
    if (node >= n) return;
    int e0 = rp[node];
    int e1 = rp[node + 1];
    float di = dinv[node];
    float a[8] = {0, 0, 0, 0, 0, 0, 0, 0};
    float c[8] = {0, 0, 0, 0, 0, 0, 0, 0};
    acc8(xs[(size_t)node * 8 + j], a);  // self term
    int e = e0;
    for (; e + 3 < e1; e += 4) {
        int s0 = col[e];
        int s1 = col[e + 1];
        int s2 = col[e + 2];
        int s3 = col[e + 3];
        uint4 u0 = xs[(size_t)s0 * 8 + j];
        uint4 u1 = xs[(size_t)s1 * 8 + j];
        uint4 u2 = xs[(size_t)s2 * 8 + j];
        uint4 u3 = xs[(size_t)s3 * 8 + j];
        acc8(u0, a);
        acc8(u1, c);
        acc8(u2, a);
        acc8(u3, c);
    }
    for (; e < e1; ++e) acc8(xs[(size_t)col[e] * 8 + j], a);
#pragma unroll
    for (int i = 0; i < 8; ++i) a[i] += c[i];
    size_t o = (size_t)node * 8 + j;
    float d2 = di * di;
    g1b[o] = pack8(a, d2);
    float fsc = d2 * 16.0f;  // fp8 carried at 16x scale
    uint2 f8;
    f8.x = enc_e4m3(a[0] * fsc) | (enc_e4m3(a[1] * fsc) << 8) |
           (enc_e4m3(a[2] * fsc) << 16) | (enc_e4m3(a[3] * fsc) << 24);
    f8.y = enc_e4m3(a[4] * fsc) | (enc_e4m3(a[5] * fsc) << 8) |
           (enc_e4m3(a[6] * fsc) << 16) | (enc_e4m3(a[7] * fsc) << 24);
    g1f8[o] = f8;
}

// ---------------- hop 2: row-sum of fp8 g1; h2b = bf16(di*acc) ----------------
// gathered terms decoded at 2^-120 scale; folded out in the final per-node scale

__global__ __launch_bounds__(256) void spmm_hop2_kernel(const int* __restrict__ rp,
                                                        const int* __restrict__ col,
                                                        const float* __restrict__ dinv,
                                                        const uint4* __restrict__ g1b,
                                                        const uint2* __restrict__ g1f8,
                                                        uint4* __restrict__ h2b, int n) {
    int t = blockIdx.x * 256 + threadIdx.x;
    int node = t >> 3;
    int j = t & 7;
    if (node >= n) return;
    int e0 = rp[node];
    int e1 = rp[node + 1];
    float di = dinv[node];
    float s8[8] = {0, 0, 0, 0, 0, 0, 0, 0};
    acc8(g1b[(size_t)node * 8 + j], s8);  // exact self term (bf16)
    float a[8] = {0, 0, 0, 0, 0, 0, 0, 0};
    float c[8] = {0, 0, 0, 0, 0, 0, 0, 0};
    int e = e0;
    for (; e + 3 < e1; e += 4) {
        int s0 = col[e];
        int s1 = col[e + 1];
        int s2 = col[e + 2];
        int s3 = col[e + 3];
        uint2 u0 = g1f8[(size_t)s0 * 8 + j];
        uint2 u1 = g1f8[(size_t)s1 * 8 + j];
        uint2 u2 = g1f8[(size_t)s2 * 8 + j];
        uint2 u3 = g1f8[(size_t)s3 * 8 + j];
        accf8(u0, a);
        accf8(u1, c);
        accf8(u2, a);
        accf8(u3, c);
    }
    for (; e < e1; ++e) accf8(g1f8[(size_t)col[e] * 8 + j], a);
    // gathered sum scale: x 2^120 (decode rebias) / 16 (storage scale); self: x di
    float fg = di * 0x1p116f;
#pragma unroll
    for (int i = 0; i < 8; ++i) a[i] = (a[i] + c[i]) * fg + s8[i] * di;
    h2b[(size_t)node * 8 + j] = pack8(a, 1.0f);
}

// ---------------- output GEMM via bf16 MFMA, dual accumulator ----------------
// out = x@W0 + diag(1/dinv)*(g1@W1) + h2@W2 + b

#define WT_LD 200

__global__ __launch_bounds__(256) void gemm_mfma_kernel(const unsigned short* __restrict__ xb,
                                                        const unsigned short* __restrict__ g1b,
                                                        const unsigned short* __restrict__ h2b,
                                                        const float* __restrict__ dinv,
                                                        const float* __restrict__ W,
                                                        const float* __restrict__ b,
                                                        float* __restrict__ out, int n) {
    __shared__ short sWt[64 * WT_LD];
    int tid = threadIdx.x;

    for (int i = tid; i < 192 * 64; i += 256) {
        int k = i >> 6;
        int c = i & 63;
        sWt[c * WT_LD + k] = f2bf(W[i]);
    }
    __syncthreads();

    int w = tid >> 6;
    int l = tid & 63;
    int lr = l & 15;
    int lk = l >> 4;
    int rbase = blockIdx.x * 64 + w * 16;

    int node = rbase + lr;
    int node_ld = node < n ? node : (n - 1);

    f32x4 accA[4] = {{0.f, 0.f, 0.f, 0.f}, {0.f, 0.f, 0.f, 0.f},
                     {0.f, 0.f, 0.f, 0.f}, {0.f, 0.f, 0.f, 0.f}};
    f32x4 accB[4] = {{0.f, 0.f, 0.f, 0.f}, {0.f, 0.f, 0.f, 0.f},
                     {0.f, 0.f, 0.f, 0.f}, {0.f, 0.f, 0.f, 0.f}};

    const unsigned short* srcs[3] = {xb, g1b, h2b};
#pragma unroll
    for (int kt = 0; kt < 6; ++kt) {
        const unsigned short* sp = srcs[kt >> 1];
        int kb = (kt & 1) * 32 + lk * 8;
        bf16x8 af = *(const bf16x8*)(sp + (size_t)node_ld * D_FEAT + kb);
        int kg = kt * 32 + lk * 8;
#pragma unroll
        for (int nt = 0; nt < 4; ++nt) {
            int c = nt * 16 + lr;
            bf16x8 bf = *(const bf16x8*)&sWt[c * WT_LD + kg];
            if ((kt >> 1) == 1)
                accB[nt] = __builtin_amdgcn_mfma_f32_16x16x32_bf16(af, bf, accB[nt], 0, 0, 0);
            else
                accA[nt] = __builtin_amdgcn_mfma_f32_16x16x32_bf16(af, bf, accA[nt], 0, 0, 0);
        }
    }

    float sd[4];
#pragma unroll
    for (int i = 0; i < 4; ++i) {
        int row = rbase + lk * 4 + i;
        sd[i] = (row < n) ? (1.0f / dinv[row]) : 0.0f;
    }

#pragma unroll
    for (int nt = 0; nt < 4; ++nt) {
        int c = nt * 16 + lr;
        float bias = b[c];
#pragma unroll
        for (int i = 0; i < 4; ++i) {
            int row = rbase + lk * 4 + i;
            if (row < n)
                out[(size_t)row * D_FEAT + c] = accA[nt][i] + sd[i] * accB[nt][i] + bias;
        }
    }
}

// ---------------- launch ----------------

static inline size_t align256(size_t x) { return (x + 255) & ~(size_t)255; }

extern "C" void kernel_launch(void* const* d_in, const int* in_sizes, int n_in,
                              void* d_out, int out_size, void* d_ws, size_t ws_size,
                              hipStream_t stream) {
    const float* x  = (const float*)d_in[0];
    const int*   ei = (const int*)d_in[1];
    const float* W  = (const float*)d_in[2];
    const float* b  = (const float*)d_in[3];
    float* out = (float*)d_out;

    int N = in_sizes[0] / D_FEAT;
    int E = in_sizes[1] / 2;
    const int* src = ei;
    const int* dst = ei + E;

    int NB = (N + BNODES - 1) / BNODES;   // 391 for N=100000 (<=512)
    int NC = (E + CHUNK - 1) / CHUNK;     // 391 for E=1.6M   (<=512)

    char* base = (char*)d_ws;
    size_t off = 0;
    int* rp      = (int*)(base + off);   off = align256(off + ((size_t)N + 1) * 4);
    float* dinv  = (float*)(base + off); off = align256(off + (size_t)N * 4);
    int* totals  = (int*)(base + off);   off = align256(off + (size_t)NBMAX * 4);
    int* bbase   = (int*)(base + off);   off = align256(off + (size_t)(NBMAX + 1) * 4);
    int* col     = (int*)(base + off);   off = align256(off + (size_t)E * 4);
    uint4* xb    = (uint4*)(base + off); off = align256(off + (size_t)N * D_FEAT * 2);
    uint4* xs    = (uint4*)(base + off); off = align256(off + (size_t)N * D_FEAT * 2);
    uint4* g1b   = (uint4*)(base + off); off = align256(off + (size_t)N * D_FEAT * 2);
    uint4* h2b   = (uint4*)(base + off); off = align256(off + (size_t)N * D_FEAT * 2);
    uint2* g1f8  = (uint2*)(base + off); off = align256(off + (size_t)N * D_FEAT);
    // transient build arrays beyond the persistent spans:
    unsigned* pairs = (unsigned*)(base + off);  // E*4 = 6.4 MB, dead after csr_kernel
    int* hist    = (int*)((char*)pairs + align256((size_t)E * 4));  // NC*NB*4

    const int BS = 256;
    int gN8 = (int)(((long long)N * 8 + BS - 1) / BS);
    int gGemm = (N + 63) / 64;

    hist_kernel<<<NC, BS, 0, stream>>>(dst, hist, E, NB);
    colscan_kernel<<<NB, 512, 0, stream>>>(hist, totals, NC, NB);
    base_kernel<<<1, 512, 0, stream>>>(totals, bbase, rp, NB, N, E);
    scatter_kernel<<<NC, BS, 0, stream>>>(src, dst, hist, bbase, pairs, E, NB);
    csr_kernel<<<NB, BS, 0, stream>>>(pairs, bbase, rp, dinv, col, N);
    convert_kernel<<<gN8, BS, 0, stream>>>(x, dinv, xb, xs, N);
    spmm_hop1_kernel<<<gN8, BS, 0, stream>>>(rp, col, dinv, xs, g1b, g1f8, N);
    spmm_hop2_kernel<<<gN8, BS, 0, stream>>>(rp, col, dinv, g1b, g1f8, h2b, N);
    gemm_mfma_kernel<<<gGemm, BS, 0, stream>>>((const unsigned short*)xb,
                                               (const unsigned short*)g1b,
                                               (const unsigned short*)h2b,
                                               dinv, W, b, out, N);
}